// Round 12
// baseline (185.688 us; speedup 1.0000x reference)
//
#include <hip/hip_runtime.h>
#include <hip/hip_bf16.h>

#define BATCH 2
#define SEQ   2048
#define DIM   1024
#define NH    16
#define HD    64
#define K_DIM 1024

typedef __attribute__((ext_vector_type(8))) short short8;
typedef __attribute__((ext_vector_type(4))) short short4v;
typedef __attribute__((ext_vector_type(4))) float f32x4;
typedef unsigned short ushort_t;

// fp32 -> bf16 bits, round-to-nearest-even
__device__ __forceinline__ unsigned short f2b(float x) {
    unsigned int u = __float_as_uint(x);
    u += 0x7FFFu + ((u >> 16) & 1u);
    return (unsigned short)(u >> 16);
}

// async global->LDS, 16B per lane; LDS dest = wave-uniform base + lane*16
#define ASYNC_COPY16(gp, lp) \
    __builtin_amdgcn_global_load_lds((const __attribute__((address_space(1))) void*)(gp), \
                                     (__attribute__((address_space(3))) void*)(lp), 16, 0, 0)

// ---------------------------------------------------------------------------
// Merged prep kernel: [0,1024) cast x; [1024,1792) transpose w_qkv;
// [1792,2048) transpose w_out. R12: transpose at 2 n-columns per lane via
// float2 reads (512B/wave per k-row, half the jobs/instructions; same bytes,
// same output layout).
// ---------------------------------------------------------------------------
__global__ __launch_bounds__(256)
void prep(const float* __restrict__ x, const float* __restrict__ w_qkv,
          const float* __restrict__ w_out, ushort_t* __restrict__ xb,
          ushort_t* __restrict__ wqb, ushort_t* __restrict__ wob)
{
    const int bid = blockIdx.x;
    if (bid < 1024) {
        constexpr int n4 = (BATCH * SEQ * DIM) / 4;
        int i = bid * 256 + threadIdx.x;
        for (; i < n4; i += 1024 * 256) {
            float4 v = ((const float4*)x)[i];
            short4v o;
            o[0] = (short)f2b(v.x); o[1] = (short)f2b(v.y);
            o[2] = (short)f2b(v.z); o[3] = (short)f2b(v.w);
            ((short4v*)xb)[i] = o;
        }
    } else {
        const int lane = threadIdx.x & 63;
        const float* src; ushort_t* dst; int N, job, jn2, jk;
        if (bid < 1792) {
            src = w_qkv; dst = wqb; N = 3072;
            job = (bid - 1024) * 4 + (threadIdx.x >> 6);   // 0..3071
            jn2 = job % 24; jk = job / 24;                 // 24 x 128
        } else {
            src = w_out; dst = wob; N = 1024;
            job = (bid - 1792) * 4 + (threadIdx.x >> 6);   // 0..1023
            jn2 = job % 8;  jk = job / 8;                  // 8 x 128
        }
        const int n0 = jn2 * 128 + lane * 2;
        const int k0 = jk * 8;
        short8 oa, ob;
        #pragma unroll
        for (int j = 0; j < 8; ++j) {
            const float2 v = *(const float2*)(src + (size_t)(k0 + j) * N + n0);
            oa[j] = (short)f2b(v.x);
            ob[j] = (short)f2b(v.y);
        }
        *(short8*)(dst + (size_t)n0 * K_DIM + k0)       = oa;
        *(short8*)(dst + (size_t)(n0 + 1) * K_DIM + k0) = ob;
    }
}

// ---------------------------------------------------------------------------
// 128x128 MFMA GEMM mainloop: BK=32, double-buffered LDS, post-barrier
// prefetch, chunk-XOR swizzle. k-loop unrolled x2, static buffer addressing,
// ds_read-first order (verified +4us in R6).
// ---------------------------------------------------------------------------
__device__ __forceinline__ void gemm_stage(const ushort_t* __restrict__ Ag,
                                           const ushort_t* __restrict__ Bg,
                                           ushort_t* As, ushort_t* Bs,
                                           int k0, int w, int r0, int c0)
{
    ASYNC_COPY16(Ag + (size_t)r0 * K_DIM + k0 + c0 * 8,        As + w * 512);
    ASYNC_COPY16(Ag + (size_t)(64 + r0) * K_DIM + k0 + c0 * 8, As + w * 512 + 2048);
    ASYNC_COPY16(Bg + (size_t)r0 * K_DIM + k0 + c0 * 8,        Bs + w * 512);
    ASYNC_COPY16(Bg + (size_t)(64 + r0) * K_DIM + k0 + c0 * 8, Bs + w * 512 + 2048);
}

__device__ __forceinline__ void mfma_gemm_tile(
    const ushort_t* __restrict__ Ag, const ushort_t* __restrict__ Bg,
    ushort_t (&As)[2][128 * 32], ushort_t (&Bs)[2][128 * 32], f32x4 acc[4][4])
{
    const int t = threadIdx.x;
    const int w = t >> 6, lane = t & 63;
    const int qd = lane >> 4, cl = lane & 15;
    const int p0 = w * 64 + lane;
    const int r0 = p0 >> 2;
    const int c0 = (p0 & 3) ^ (r0 & 3);

    const ushort_t* aB[4];
    const ushort_t* bB[4];
    #pragma unroll
    for (int rt = 0; rt < 4; ++rt) {
        const int row = (w >> 1) * 64 + rt * 16 + cl;
        aB[rt] = As[0] + row * 32 + ((qd ^ (row & 3)) * 8);
    }
    #pragma unroll
    for (int ct = 0; ct < 4; ++ct) {
        const int col = (w & 1) * 64 + ct * 16 + cl;
        bB[ct] = Bs[0] + col * 32 + ((qd ^ (col & 3)) * 8);
    }

    gemm_stage(Ag, Bg, As[0], Bs[0], 0, w, r0, c0);

    for (int kp = 0; kp < K_DIM / 64; ++kp) {
        __syncthreads();
        {
            short8 af[4], bfr[4];
            #pragma unroll
            for (int rt = 0; rt < 4; ++rt) af[rt] = *(const short8*)(aB[rt]);
            #pragma unroll
            for (int ct = 0; ct < 4; ++ct) bfr[ct] = *(const short8*)(bB[ct]);
            gemm_stage(Ag, Bg, As[1], Bs[1], kp * 64 + 32, w, r0, c0);
            #pragma unroll
            for (int rt = 0; rt < 4; ++rt)
                #pragma unroll
                for (int ct = 0; ct < 4; ++ct)
                    acc[rt][ct] = __builtin_amdgcn_mfma_f32_16x16x32_bf16(
                        af[rt], bfr[ct], acc[rt][ct], 0, 0, 0);
        }
        __syncthreads();
        {
            short8 af[4], bfr[4];
            #pragma unroll
            for (int rt = 0; rt < 4; ++rt) af[rt] = *(const short8*)(aB[rt] + 4096);
            #pragma unroll
            for (int ct = 0; ct < 4; ++ct) bfr[ct] = *(const short8*)(bB[ct] + 4096);
            if (kp + 1 < K_DIM / 64)
                gemm_stage(Ag, Bg, As[0], Bs[0], kp * 64 + 64, w, r0, c0);
            #pragma unroll
            for (int rt = 0; rt < 4; ++rt)
                #pragma unroll
                for (int ct = 0; ct < 4; ++ct)
                    acc[rt][ct] = __builtin_amdgcn_mfma_f32_16x16x32_bf16(
                        af[rt], bfr[ct], acc[rt][ct], 0, 0, 0);
        }
    }
}

// ---------------------------------------------------------------------------
// GEMM1: qkv = xb @ wqb^T with fused RoPE + bf16 stores (d' = cl*4+ct perm).
// XCD-aware block swizzle (bijective, 768%8==0): each XCD gets 4 consecutive
// m-panels x all 24 n-tiles -> A-panels stay L2-resident.
// ---------------------------------------------------------------------------
__global__ __launch_bounds__(256, 3)
void gemm_qkv_mfma(const ushort_t* __restrict__ xb, const ushort_t* __restrict__ wqb,
                   ushort_t* __restrict__ qb, ushort_t* __restrict__ kb,
                   ushort_t* __restrict__ vt,
                   const float* __restrict__ cosb, const float* __restrict__ sinb)
{
    __shared__ __align__(16) ushort_t As[2][128 * 32];
    __shared__ __align__(16) ushort_t Bs[2][128 * 32];
    const int id  = blockIdx.y * 24 + blockIdx.x;          // 0..767
    const int id2 = (id & 7) * 96 + (id >> 3);             // XCD-contiguous
    const int bx  = id2 % 24, by = id2 / 24;
    const int m0 = by * 128, n0 = bx * 128;

    f32x4 acc[4][4];
    #pragma unroll
    for (int i = 0; i < 4; ++i)
        #pragma unroll
        for (int j = 0; j < 4; ++j)
            #pragma unroll
            for (int r = 0; r < 4; ++r) acc[i][j][r] = 0.f;

    mfma_gemm_tile(xb + (size_t)m0 * K_DIM, wqb + (size_t)n0 * K_DIM, As, Bs, acc);

    const int t = threadIdx.x, w = t >> 6, lane = t & 63;
    const int qd = lane >> 4, cl = lane & 15;
    const int b = m0 >> 11;
    const int lbase = (m0 & 2047) + (w >> 1) * 64;
    const int region = bx >> 3;                      // 0=q, 1=k, 2=v
    const int h = (bx & 7) * 2 + (w & 1);

    if (region < 2) {
        ushort_t* dst = region ? kb : qb;
        const float sc = region ? 1.0f : 0.18033688011111234f;  // 0.125*log2(e)
        #pragma unroll
        for (int rt = 0; rt < 4; ++rt) {
            #pragma unroll
            for (int r = 0; r < 4; ++r) {
                const int l = lbase + rt * 16 + qd * 4 + r;
                const float c0 = cosb[l * HD + cl],      s0 = sinb[l * HD + cl];
                const float c1 = cosb[l * HD + 16 + cl], s1 = sinb[l * HD + 16 + cl];
                const float v0 = acc[rt][0][r] * c0 - acc[rt][2][r] * s0;
                const float v1 = acc[rt][1][r] * c1 - acc[rt][3][r] * s1;
                const float v2 = acc[rt][2][r] * c0 + acc[rt][0][r] * s0;
                const float v3 = acc[rt][3][r] * c1 + acc[rt][1][r] * s1;
                short4v o4;
                o4[0] = (short)f2b(v0 * sc);
                o4[1] = (short)f2b(v1 * sc);
                o4[2] = (short)f2b(v2 * sc);
                o4[3] = (short)f2b(v3 * sc);
                *(short4v*)(dst + (((size_t)b * NH + h) * SEQ + l) * HD + cl * 4) = o4;
            }
        }
    } else {
        #pragma unroll
        for (int rt = 0; rt < 4; ++rt)
            #pragma unroll
            for (int ct = 0; ct < 4; ++ct) {
                const int d = ct * 16 + cl;
                const int l = lbase + rt * 16 + qd * 4;
                short4v o4;
                #pragma unroll
                for (int r = 0; r < 4; ++r) o4[r] = (short)f2b(acc[rt][ct][r]);
                *(short4v*)(vt + (((size_t)b * NH + h) * HD + d) * SEQ + l) = o4;
            }
    }
}

// ---------------------------------------------------------------------------
// GEMM2: out = ob @ wob^T, 128x64 tiles (512 blocks -> 2 blocks/CU), fp32
// store. 4-buffer PAIR staging (R10-verified). XCD-aware swizzle (R11).
// ---------------------------------------------------------------------------
__device__ __forceinline__ void go_stage(const ushort_t* __restrict__ Ag,
                                         const ushort_t* __restrict__ Bg,
                                         ushort_t* As, ushort_t* Bs,
                                         int k0, int w, int lane)
{
    #pragma unroll
    for (int j = 0; j < 2; ++j) {
        const int r = w * 32 + j * 16 + (lane >> 2);
        const int c = (lane & 3) ^ (r & 3);
        ASYNC_COPY16(Ag + (size_t)r * K_DIM + k0 + c * 8, As + (w * 128 + j * 64) * 8);
    }
    const int rb = w * 16 + (lane >> 2);
    const int cb = (lane & 3) ^ (rb & 3);
    ASYNC_COPY16(Bg + (size_t)rb * K_DIM + k0 + cb * 8, Bs + (w * 64) * 8);
}

__global__ __launch_bounds__(256, 3)
void gemm_out_mfma(const ushort_t* __restrict__ ob, const ushort_t* __restrict__ wob,
                   float* __restrict__ out)
{
    __shared__ __align__(16) ushort_t As[4][128 * 32];   // 32KB
    __shared__ __align__(16) ushort_t Bs[4][64 * 32];    // 16KB
    const int id  = blockIdx.y * 16 + blockIdx.x;        // 0..511
    const int id2 = (id & 7) * 64 + (id >> 3);           // XCD-contiguous
    const int bx  = id2 & 15, by = id2 >> 4;
    const int m0 = by * 128, n0 = bx * 64;
    const int t = threadIdx.x;
    const int w = t >> 6, lane = t & 63;
    const int qd = lane >> 4, cl = lane & 15;
    const int wr = w >> 1, wc = w & 1;

    f32x4 acc[4][2];
    #pragma unroll
    for (int i = 0; i < 4; ++i)
        #pragma unroll
        for (int j = 0; j < 2; ++j)
            #pragma unroll
            for (int r = 0; r < 4; ++r) acc[i][j][r] = 0.f;

    const ushort_t* Ag = ob  + (size_t)m0 * K_DIM;
    const ushort_t* Bg = wob + (size_t)n0 * K_DIM;

    const ushort_t* aB[4];
    const ushort_t* bB[2];
    #pragma unroll
    for (int rt = 0; rt < 4; ++rt) {
        const int row = wr * 64 + rt * 16 + cl;
        aB[rt] = As[0] + row * 32 + ((qd ^ (row & 3)) * 8);
    }
    #pragma unroll
    for (int ct = 0; ct < 2; ++ct) {
        const int col = wc * 32 + ct * 16 + cl;
        bB[ct] = Bs[0] + col * 32 + ((qd ^ (col & 3)) * 8);
    }

    // prologue: stage steps 0,1 into buffers 0,1
    go_stage(Ag, Bg, As[0], Bs[0], 0,  w, lane);
    go_stage(Ag, Bg, As[1], Bs[1], 32, w, lane);

    #define GO_STEP(BUF)                                                        \
        {                                                                       \
            short8 af[4], bfr[2];                                               \
            _Pragma("unroll")                                                   \
            for (int rt = 0; rt < 4; ++rt)                                      \
                af[rt] = *(const short8*)(aB[rt] + (BUF) * 4096);               \
            _Pragma("unroll")                                                   \
            for (int ct = 0; ct < 2; ++ct)                                      \
                bfr[ct] = *(const short8*)(bB[ct] + (BUF) * 2048);              \
            _Pragma("unroll")                                                   \
            for (int rt = 0; rt < 4; ++rt)                                      \
                _Pragma("unroll")                                               \
                for (int ct = 0; ct < 2; ++ct)                                  \
                    acc[rt][ct] = __builtin_amdgcn_mfma_f32_16x16x32_bf16(      \
                        af[rt], bfr[ct], acc[rt][ct], 0, 0, 0);                 \
        }

    for (int r = 0; r < K_DIM / 128; ++r) {          // 8 rounds x 4 steps
        __syncthreads();
        go_stage(Ag, Bg, As[2], Bs[2], (4 * r + 2) * 32, w, lane);
        go_stage(Ag, Bg, As[3], Bs[3], (4 * r + 3) * 32, w, lane);
        GO_STEP(0)
        GO_STEP(1)
        __syncthreads();
        if (r + 1 < K_DIM / 128) {
            go_stage(Ag, Bg, As[0], Bs[0], (4 * r + 4) * 32, w, lane);
            go_stage(Ag, Bg, As[1], Bs[1], (4 * r + 5) * 32, w, lane);
        }
        GO_STEP(2)
        GO_STEP(3)
    }
    #undef GO_STEP

    const int mbase = m0 + wr * 64, nbase = n0 + wc * 32;
    #pragma unroll
    for (int rt = 0; rt < 4; ++rt)
        #pragma unroll
        for (int ct = 0; ct < 2; ++ct)
            #pragma unroll
            for (int r = 0; r < 4; ++r)
                out[(size_t)(mbase + rt * 16 + qd * 4 + r) * DIM + nbase + ct * 16 + cl] =
                    acc[rt][ct][r];
}

// ---------------------------------------------------------------------------
// Flash attention v11 (R6/R10-verified best, ~54us at nominal clock): pair
// processing -- one __syncthreads + one vmcnt-drain per 128 k-positions.
// 4 K-buffers + 4 V-buffers (64KB LDS, 2 blocks/CU). PV-deferral across
// tiles/barriers via alternating register sets.
// Ledger: no VGPR cap <128 (R7 spill); no <2 waves/SIMD (R9); nt>2, split-K
// null (R8/R9); V stays LDS-staged (R5 fail). Grid h-fastest = XCD-local K/V.
// ---------------------------------------------------------------------------
#define QK_MFMA(kfv, sdst)                                                      \
    _Pragma("unroll")                                                           \
    for (int mt = 0; mt < 4; ++mt)                                              \
        _Pragma("unroll")                                                       \
        for (int nt = 0; nt < 2; ++nt)                                          \
            sdst[mt][nt] = __builtin_amdgcn_mfma_f32_16x16x32_bf16(             \
                kfv[mt][0], qf[nt][0], fz, 0, 0, 0);                            \
    _Pragma("unroll")                                                           \
    for (int mt = 0; mt < 4; ++mt)                                              \
        _Pragma("unroll")                                                       \
        for (int nt = 0; nt < 2; ++nt)                                          \
            sdst[mt][nt] = __builtin_amdgcn_mfma_f32_16x16x32_bf16(             \
                kfv[mt][1], qf[nt][1], sdst[mt][nt], 0, 0, 0);

#define PV_MFMA(vfv, pfv)                                                       \
    _Pragma("unroll")                                                           \
    for (int kh = 0; kh < 2; ++kh)                                              \
        _Pragma("unroll")                                                       \
        for (int dt = 0; dt < 4; ++dt)                                          \
            _Pragma("unroll")                                                   \
            for (int nt = 0; nt < 2; ++nt)                                      \
                oaccT[dt][nt] = __builtin_amdgcn_mfma_f32_16x16x32_bf16(        \
                    vfv[dt][kh], pfv[nt][kh], oaccT[dt][nt], 0, 0, 0);

#define L_MFMA(pfv)                                                             \
    _Pragma("unroll")                                                           \
    for (int kh = 0; kh < 2; ++kh)                                              \
        _Pragma("unroll")                                                       \
        for (int nt = 0; nt < 2; ++nt)                                          \
            lacc[nt] = __builtin_amdgcn_mfma_f32_16x16x32_bf16(                 \
                onesA, pfv[nt][kh], lacc[nt], 0, 0, 0);

#define EXPPACK(sv, pfD)                                                        \
    _Pragma("unroll")                                                           \
    for (int nt = 0; nt < 2; ++nt) {                                            \
        unsigned int wr2[4][2];                                                 \
        _Pragma("unroll")                                                       \
        for (int mt = 0; mt < 4; ++mt) {                                        \
            const float e0 = __builtin_amdgcn_exp2f(sv[mt][nt][0]);             \
            const float e1 = __builtin_amdgcn_exp2f(sv[mt][nt][1]);             \
            const float e2 = __builtin_amdgcn_exp2f(sv[mt][nt][2]);             \
            const float e3 = __builtin_amdgcn_exp2f(sv[mt][nt][3]);             \
            union { __hip_bfloat162 h2; unsigned int u; } pk0, pk1;             \
            pk0.h2 = __float22bfloat162_rn(make_float2(e0, e1));                \
            pk1.h2 = __float22bfloat162_rn(make_float2(e2, e3));                \
            wr2[mt][0] = pk0.u;                                                 \
            wr2[mt][1] = pk1.u;                                                 \
        }                                                                       \
        _Pragma("unroll")                                                       \
        for (int kh = 0; kh < 2; ++kh) {                                        \
            union { unsigned int u[4]; short8 s8; } pu;                         \
            _Pragma("unroll")                                                   \
            for (int i = 0; i < 2; ++i) {                                       \
                unsigned int a  = wr2[2 * kh][i];                               \
                unsigned int bb = wr2[2 * kh + 1][i];                           \
                asm("v_permlane32_swap_b32 %0, %1" : "+v"(a), "+v"(bb));        \
                asm("v_permlane16_swap_b32 %0, %1" : "+v"(a), "+v"(bb));        \
                pu.u[i]     = a;                                                \
                pu.u[2 + i] = bb;                                               \
            }                                                                   \
            pfD[nt][kh] = pu.s8;                                                \
        }                                                                       \
    }

// One pair: tile A in buffer at BOFF, tile B at BOFF+4096 (ushort units).
// Consumes persistent set (pfC,vfC); produces (pfP,vfP).
#define PAIR_BODY(BOFF, pfC, vfC, pfP, vfP)                                     \
    {                                                                           \
        short8 kf[4][2], vfT[4][2], pfT[2][2];                                  \
        f32x4 s[4][2];                                                          \
        /* ---- tile A ---- */                                                  \
        _Pragma("unroll")                                                       \
        for (int mt = 0; mt < 4; ++mt) {                                        \
            kf[mt][0] = *(const short8*)(kb0 + (BOFF) + mt * 1024);             \
            kf[mt][1] = *(const short8*)(kb1 + (BOFF) + mt * 1024);             \
        }                                                                       \
        _Pragma("unroll")                                                       \
        for (int dt = 0; dt < 4; ++dt) {                                        \
            vfT[dt][0] = *(const short8*)(vb0 + (BOFF) + dt * 1024);            \
            vfT[dt][1] = *(const short8*)(vb1 + (BOFF) + dt * 1024);            \
        }                                                                       \
        __builtin_amdgcn_s_setprio(1);                                          \
        QK_MFMA(kf, s)                                                          \
        PV_MFMA(vfC, pfC)                                                       \
        __builtin_amdgcn_s_setprio(0);                                          \
        EXPPACK(s, pfT)                                                         \
        L_MFMA(pfT)                                                             \
        /* ---- tile B ---- */                                                  \
        _Pragma("unroll")                                                       \
        for (int mt = 0; mt < 4; ++mt) {                                        \
            kf[mt][0] = *(const short8*)(kb0 + (BOFF) + 4096 + mt * 1024);      \
            kf[mt][1] = *(const short8*)(kb1 + (BOFF) + 4096 + mt * 1024);      \
        }                                                                       \
        _Pragma("unroll")                                                       \
        for (int dt = 0; dt < 4; ++dt) {                                        \
            vfP[dt][0] = *(const short8*)(vb0 + (BOFF) + 4096 + dt * 1024);     \
            vfP[dt][1] = *(const short8*)(vb1 + (BOFF) + 4096 + dt * 1024);     \
        }                                                                       \
        __builtin_amdgcn_s_setprio(1);                                          \
        QK_MFMA(kf, s)                                                          \
        PV_MFMA(vfT, pfT)                                                       \
        __builtin_amdgcn_s_setprio(0);                                          \
        EXPPACK(s, pfP)                                                         \
        L_MFMA(pfP)                                                             \
    }

__global__ __launch_bounds__(256, 2)
void attn_mfma(const ushort_t* __restrict__ qb, const ushort_t* __restrict__ kb,
               const ushort_t* __restrict__ vt, ushort_t* __restrict__ ob)
{
    const int h = blockIdx.x;                 // fastest -> K/V sharers on one XCD
    const int b = blockIdx.y;
    const int qt = blockIdx.z;                // 0..15, 128 queries per block
    const int t = threadIdx.x;
    const int w = t >> 6, lane = t & 63;
    const int qd = lane >> 4, cl = lane & 15;

    __shared__ __align__(16) ushort_t Ks[4][64 * 64];   // 32KB
    __shared__ __align__(16) ushort_t Vs[4][64 * 64];   // 32KB

    const size_t bh = (size_t)b * NH + h;
    const ushort_t* qbase = qb + (bh * SEQ + qt * 128 + w * 32) * HD;
    const ushort_t* kbase = kb + bh * SEQ * HD;
    const ushort_t* vbase = vt + bh * (size_t)HD * SEQ;

    const int p0 = w * 128 + lane;
    const int r0a = p0 >> 3,  c0a = (p0 & 7) ^ (r0a & 7);
    const int p1 = p0 + 64;
    const int r1a = p1 >> 3,  c1a = (p1 & 7) ^ (r1a & 7);
    const int ldsoff0 = (w * 128) * 8;
    const int ldsoff1 = (w * 128 + 64) * 8;

    // staging pointers, advanced two 64-tiles per stage
    const ushort_t* kg0 = kbase + (size_t)r0a * HD + c0a * 8;
    const ushort_t* kg1 = kbase + (size_t)r1a * HD + c1a * 8;
    const ushort_t* vg0 = vbase + (size_t)r0a * SEQ + c0a * 8;
    const ushort_t* vg1 = vbase + (size_t)r1a * SEQ + c1a * 8;

    // hoisted LDS read bases (buffer 0); buffers 1..3 via +4096k immediates
    const int lo0 = (cl * 8 + (qd ^ (cl & 7))) * 8;
    const int lo1 = (cl * 8 + ((4 + qd) ^ (cl & 7))) * 8;
    const ushort_t* kb0 = Ks[0] + lo0; const ushort_t* kb1 = Ks[0] + lo1;
    const ushort_t* vb0 = Vs[0] + lo0; const ushort_t* vb1 = Vs[0] + lo1;

    short8 qf[2][2];
    #pragma unroll
    for (int nt = 0; nt < 2; ++nt)
        #pragma unroll
        for (int kh = 0; kh < 2; ++kh)
            qf[nt][kh] = *(const short8*)(qbase + (nt * 16 + cl) * HD + kh * 32 + qd * 8);

    const f32x4 fz = {0.f, 0.f, 0.f, 0.f};
    short8 onesA;
    #pragma unroll
    for (int e = 0; e < 8; ++e) onesA[e] = (short)0x3F80;   // bf16 1.0

    f32x4 oaccT[4][2];
    f32x4 lacc[2];
    #pragma unroll
    for (int dt = 0; dt < 4; ++dt)
        #pragma unroll
        for (int nt = 0; nt < 2; ++nt)
            #pragma unroll
            for (int r = 0; r < 4; ++r) oaccT[dt][nt][r] = 0.f;
    #pragma unroll
    for (int nt = 0; nt < 2; ++nt)
        #pragma unroll
        for (int r = 0; r < 4; ++r) lacc[nt][r] = 0.f;

    // persistent deferred-PV sets; set-23 zeroed (first pair consumes it)
    short8 pf01[2][2], vf01[4][2], pf23[2][2], vf23[4][2];
    #pragma unroll
    for (int nt = 0; nt < 2; ++nt)
        #pragma unroll
        for (int kh = 0; kh < 2; ++kh)
            #pragma unroll
            for (int e = 0; e < 8; ++e) pf23[nt][kh][e] = 0;
    #pragma unroll
    for (int dt = 0; dt < 4; ++dt)
        #pragma unroll
        for (int kh = 0; kh < 2; ++kh)
            #pragma unroll
            for (int e = 0; e < 8; ++e) vf23[dt][kh][e] = 0;

    {   // stage tiles 0,1 into buffers 0,1
        ASYNC_COPY16(kg0,            (ushort_t*)Ks[0] + ldsoff0);
        ASYNC_COPY16(kg1,            (ushort_t*)Ks[0] + ldsoff1);
        ASYNC_COPY16(vg0,            (ushort_t*)Vs[0] + ldsoff0);
        ASYNC_COPY16(vg1,            (ushort_t*)Vs[0] + ldsoff1);
        ASYNC_COPY16(kg0 + 64 * HD,  (ushort_t*)Ks[1] + ldsoff0);
        ASYNC_COPY16(kg1 + 64 * HD,  (ushort_t*)Ks[1] + ldsoff1);
        ASYNC_COPY16(vg0 + 64,       (ushort_t*)Vs[1] + ldsoff0);
        ASYNC_COPY16(vg1 + 64,       (ushort_t*)Vs[1] + ldsoff1);
        kg0 += 128 * HD; kg1 += 128 * HD; vg0 += 128; vg1 += 128;
    }

    for (int q8 = 0; q8 < 8; ++q8) {
        // ======== pair A: tiles 4q8,4q8+1 in buffers {0,1} ========
        __syncthreads();
        {   // stage tiles 4q8+2,4q8+3 -> buffers {2,3} (always valid)
            ASYNC_COPY16(kg0,            (ushort_t*)Ks[2] + ldsoff0);
            ASYNC_COPY16(kg1,            (ushort_t*)Ks[2] + ldsoff1);
            ASYNC_COPY16(vg0,            (ushort_t*)Vs[2] + ldsoff0);
            ASYNC_COPY16(vg1,            (ushort_t*)Vs[2] + ldsoff1);
            ASYNC_COPY16(kg0 + 64 * HD,  (ushort_t*)Ks[3] + ldsoff0);
            ASYNC_COPY16(kg1 + 64 * HD,  (ushort_t*)Ks[3] + ldsoff1);
            ASYNC_COPY16(vg0 + 64,       (ushort_t*)Vs[3] + ldsoff0);
            ASYNC_COPY16(vg1 + 64,       (ushort_t*)Vs[3] + ldsoff1);
            kg0 += 128 * HD; kg1 += 128 * HD; vg0 += 128; vg1 += 128;
        }
        PAIR_BODY(0, pf23, vf23, pf01, vf01)

        // ======== pair B: tiles 4q8+2,4q8+3 in buffers {2,3} ========
        __syncthreads();
        if (q8 + 1 < 8) {   // stage tiles 4q8+4,4q8+5 -> buffers {0,1}
            ASYNC_COPY16(kg0,            (ushort_t*)Ks[0] + ldsoff0);
            ASYNC_COPY16(kg1,            (ushort_t*)Ks[0] + ldsoff1);
            ASYNC_COPY16(vg0,            (ushort_t*)Vs[0] + ldsoff0);
            ASYNC_COPY16(vg1,            (ushort_t*)Vs[0] + ldsoff1);
            ASYNC_COPY16(kg0 + 64 * HD,  (ushort_t*)Ks[1] + ldsoff0);
            ASYNC_COPY16(kg1 + 64 * HD,  (ushort_t*)Ks[1] + ldsoff1);
            ASYNC_COPY16(vg0 + 64,       (ushort_t*)Vs[1] + ldsoff0);
            ASYNC_COPY16(vg1 + 64,       (ushort_t*)Vs[1] + ldsoff1);
            kg0 += 128 * HD; kg1 += 128 * HD; vg0 += 128; vg1 += 128;
        }
        PAIR_BODY(8192, pf01, vf01, pf23, vf23)
    }

    // tail PV for the last tile (pair B of q8=7 produced pf23/vf23)
    PV_MFMA(vf23, pf23)

    // ---- epilogue: l comes straight from lacc (all rows equal) ----
    #pragma unroll
    for (int nt = 0; nt < 2; ++nt) {
        const float inv = 1.0f / lacc[nt][0];
        const int query = qt * 128 + w * 32 + nt * 16 + cl;
        ushort_t* op = ob + ((size_t)b * SEQ + query) * DIM + h * HD;
        #pragma unroll
        for (int dt = 0; dt < 4; ++dt) {
            short4v o4;
            #pragma unroll
            for (int r = 0; r < 4; ++r) o4[r] = (short)f2b(oaccT[dt][nt][r] * inv);
            *(short4v*)(op + dt * 16 + qd * 4) = o4;
        }
    }
}

// ---------------------------------------------------------------------------
extern "C" void kernel_launch(void* const* d_in, const int* in_sizes, int n_in,
                              void* d_out, int out_size, void* d_ws, size_t ws_size,
                              hipStream_t stream)
{
    const float* x     = (const float*)d_in[0];
    const float* cosb  = (const float*)d_in[1];
    const float* sinb  = (const float*)d_in[2];
    const float* w_qkv = (const float*)d_in[3];
    const float* w_out = (const float*)d_in[4];
    float* out = (float*)d_out;

    // workspace layout (peak 48MB, no aliasing hazards):
    //  [0,8)   qb   [8,16) kb   [16,24) vt   [24,26) wob
    //  [26,34) ob   [34,42) xb  [42,48) wqb
    constexpr size_t MB = 1u << 20;
    char* ws = (char*)d_ws;
    ushort_t* qb  = (ushort_t*)(ws);
    ushort_t* kb  = (ushort_t*)(ws + 8 * MB);
    ushort_t* vt  = (ushort_t*)(ws + 16 * MB);
    ushort_t* wob = (ushort_t*)(ws + 24 * MB);
    ushort_t* ob  = (ushort_t*)(ws + 26 * MB);
    ushort_t* xb  = (ushort_t*)(ws + 34 * MB);
    ushort_t* wqb = (ushort_t*)(ws + 42 * MB);

    prep<<<2048, 256, 0, stream>>>(x, w_qkv, w_out, xb, wqb, wob);
    gemm_qkv_mfma<<<dim3(24, 32), 256, 0, stream>>>(xb, wqb, qb, kb, vt, cosb, sinb);
    attn_mfma<<<dim3(16, 2, 16), 256, 0, stream>>>(qb, kb, vt, ob);
    gemm_out_mfma<<<dim3(16, 32), 256, 0, stream>>>(ob, wob, out);
}

// Round 13
// 182.485 us; speedup vs baseline: 1.0176x; 1.0176x over previous
//
#include <hip/hip_runtime.h>
#include <hip/hip_bf16.h>

#define BATCH 2
#define SEQ   2048
#define DIM   1024
#define NH    16
#define HD    64
#define K_DIM 1024

typedef __attribute__((ext_vector_type(8))) short short8;
typedef __attribute__((ext_vector_type(4))) short short4v;
typedef __attribute__((ext_vector_type(4))) float f32x4;
typedef unsigned short ushort_t;

// fp32 -> bf16 bits, round-to-nearest-even
__device__ __forceinline__ unsigned short f2b(float x) {
    unsigned int u = __float_as_uint(x);
    u += 0x7FFFu + ((u >> 16) & 1u);
    return (unsigned short)(u >> 16);
}

// async global->LDS, 16B per lane; LDS dest = wave-uniform base + lane*16
#define ASYNC_COPY16(gp, lp) \
    __builtin_amdgcn_global_load_lds((const __attribute__((address_space(1))) void*)(gp), \
                                     (__attribute__((address_space(3))) void*)(lp), 16, 0, 0)

// ---------------------------------------------------------------------------
// Merged prep kernel (R11-verified best): [0,1024) cast x; [1024,2560)
// transpose w_qkv; [2560,3072) transpose w_out. (R12's float2 2-col variant
// was neutral-to-negative; reverted.)
// ---------------------------------------------------------------------------
__global__ __launch_bounds__(256)
void prep(const float* __restrict__ x, const float* __restrict__ w_qkv,
          const float* __restrict__ w_out, ushort_t* __restrict__ xb,
          ushort_t* __restrict__ wqb, ushort_t* __restrict__ wob)
{
    const int bid = blockIdx.x;
    if (bid < 1024) {
        constexpr int n4 = (BATCH * SEQ * DIM) / 4;
        int i = bid * 256 + threadIdx.x;
        for (; i < n4; i += 1024 * 256) {
            float4 v = ((const float4*)x)[i];
            short4v o;
            o[0] = (short)f2b(v.x); o[1] = (short)f2b(v.y);
            o[2] = (short)f2b(v.z); o[3] = (short)f2b(v.w);
            ((short4v*)xb)[i] = o;
        }
    } else {
        const int lane = threadIdx.x & 63;
        const float* src; ushort_t* dst; int N, job;
        if (bid < 2560) { src = w_qkv; dst = wqb; N = 3072; job = (bid - 1024) * 4 + (threadIdx.x >> 6); }
        else            { src = w_out; dst = wob; N = 1024; job = (bid - 2560) * 4 + (threadIdx.x >> 6); }
        const int jn = (N == 3072) ? (job % 48) : (job % 16);
        const int jk = (N == 3072) ? (job / 48) : (job / 16);
        const int n  = jn * 64 + lane;
        const int k0 = jk * 8;
        short8 o;
        #pragma unroll
        for (int j = 0; j < 8; ++j) o[j] = (short)f2b(src[(size_t)(k0 + j) * N + n]);
        *(short8*)(dst + (size_t)n * K_DIM + k0) = o;
    }
}

// ---------------------------------------------------------------------------
// 128x128 MFMA GEMM mainloop: BK=32, double-buffered LDS, post-barrier
// prefetch, chunk-XOR swizzle. k-loop unrolled x2, static buffer addressing,
// ds_read-first order (verified +4us in R6).
// ---------------------------------------------------------------------------
__device__ __forceinline__ void gemm_stage(const ushort_t* __restrict__ Ag,
                                           const ushort_t* __restrict__ Bg,
                                           ushort_t* As, ushort_t* Bs,
                                           int k0, int w, int r0, int c0)
{
    ASYNC_COPY16(Ag + (size_t)r0 * K_DIM + k0 + c0 * 8,        As + w * 512);
    ASYNC_COPY16(Ag + (size_t)(64 + r0) * K_DIM + k0 + c0 * 8, As + w * 512 + 2048);
    ASYNC_COPY16(Bg + (size_t)r0 * K_DIM + k0 + c0 * 8,        Bs + w * 512);
    ASYNC_COPY16(Bg + (size_t)(64 + r0) * K_DIM + k0 + c0 * 8, Bs + w * 512 + 2048);
}

__device__ __forceinline__ void mfma_gemm_tile(
    const ushort_t* __restrict__ Ag, const ushort_t* __restrict__ Bg,
    ushort_t (&As)[2][128 * 32], ushort_t (&Bs)[2][128 * 32], f32x4 acc[4][4])
{
    const int t = threadIdx.x;
    const int w = t >> 6, lane = t & 63;
    const int qd = lane >> 4, cl = lane & 15;
    const int p0 = w * 64 + lane;
    const int r0 = p0 >> 2;
    const int c0 = (p0 & 3) ^ (r0 & 3);

    const ushort_t* aB[4];
    const ushort_t* bB[4];
    #pragma unroll
    for (int rt = 0; rt < 4; ++rt) {
        const int row = (w >> 1) * 64 + rt * 16 + cl;
        aB[rt] = As[0] + row * 32 + ((qd ^ (row & 3)) * 8);
    }
    #pragma unroll
    for (int ct = 0; ct < 4; ++ct) {
        const int col = (w & 1) * 64 + ct * 16 + cl;
        bB[ct] = Bs[0] + col * 32 + ((qd ^ (col & 3)) * 8);
    }

    gemm_stage(Ag, Bg, As[0], Bs[0], 0, w, r0, c0);

    for (int kp = 0; kp < K_DIM / 64; ++kp) {
        __syncthreads();
        {
            short8 af[4], bfr[4];
            #pragma unroll
            for (int rt = 0; rt < 4; ++rt) af[rt] = *(const short8*)(aB[rt]);
            #pragma unroll
            for (int ct = 0; ct < 4; ++ct) bfr[ct] = *(const short8*)(bB[ct]);
            gemm_stage(Ag, Bg, As[1], Bs[1], kp * 64 + 32, w, r0, c0);
            #pragma unroll
            for (int rt = 0; rt < 4; ++rt)
                #pragma unroll
                for (int ct = 0; ct < 4; ++ct)
                    acc[rt][ct] = __builtin_amdgcn_mfma_f32_16x16x32_bf16(
                        af[rt], bfr[ct], acc[rt][ct], 0, 0, 0);
        }
        __syncthreads();
        {
            short8 af[4], bfr[4];
            #pragma unroll
            for (int rt = 0; rt < 4; ++rt) af[rt] = *(const short8*)(aB[rt] + 4096);
            #pragma unroll
            for (int ct = 0; ct < 4; ++ct) bfr[ct] = *(const short8*)(bB[ct] + 4096);
            if (kp + 1 < K_DIM / 64)
                gemm_stage(Ag, Bg, As[0], Bs[0], kp * 64 + 64, w, r0, c0);
            #pragma unroll
            for (int rt = 0; rt < 4; ++rt)
                #pragma unroll
                for (int ct = 0; ct < 4; ++ct)
                    acc[rt][ct] = __builtin_amdgcn_mfma_f32_16x16x32_bf16(
                        af[rt], bfr[ct], acc[rt][ct], 0, 0, 0);
        }
    }
}

// ---------------------------------------------------------------------------
// GEMM1: qkv = xb @ wqb^T with fused RoPE + bf16 stores (d' = cl*4+ct perm).
// XCD-aware block swizzle (bijective, 768%8==0): each XCD gets 4 consecutive
// m-panels x all 24 n-tiles -> A-panels stay L2-resident.
// ---------------------------------------------------------------------------
__global__ __launch_bounds__(256, 3)
void gemm_qkv_mfma(const ushort_t* __restrict__ xb, const ushort_t* __restrict__ wqb,
                   ushort_t* __restrict__ qb, ushort_t* __restrict__ kb,
                   ushort_t* __restrict__ vt,
                   const float* __restrict__ cosb, const float* __restrict__ sinb)
{
    __shared__ __align__(16) ushort_t As[2][128 * 32];
    __shared__ __align__(16) ushort_t Bs[2][128 * 32];
    const int id  = blockIdx.y * 24 + blockIdx.x;          // 0..767
    const int id2 = (id & 7) * 96 + (id >> 3);             // XCD-contiguous
    const int bx  = id2 % 24, by = id2 / 24;
    const int m0 = by * 128, n0 = bx * 128;

    f32x4 acc[4][4];
    #pragma unroll
    for (int i = 0; i < 4; ++i)
        #pragma unroll
        for (int j = 0; j < 4; ++j)
            #pragma unroll
            for (int r = 0; r < 4; ++r) acc[i][j][r] = 0.f;

    mfma_gemm_tile(xb + (size_t)m0 * K_DIM, wqb + (size_t)n0 * K_DIM, As, Bs, acc);

    const int t = threadIdx.x, w = t >> 6, lane = t & 63;
    const int qd = lane >> 4, cl = lane & 15;
    const int b = m0 >> 11;
    const int lbase = (m0 & 2047) + (w >> 1) * 64;
    const int region = bx >> 3;                      // 0=q, 1=k, 2=v
    const int h = (bx & 7) * 2 + (w & 1);

    if (region < 2) {
        ushort_t* dst = region ? kb : qb;
        const float sc = region ? 1.0f : 0.18033688011111234f;  // 0.125*log2(e)
        #pragma unroll
        for (int rt = 0; rt < 4; ++rt) {
            #pragma unroll
            for (int r = 0; r < 4; ++r) {
                const int l = lbase + rt * 16 + qd * 4 + r;
                const float c0 = cosb[l * HD + cl],      s0 = sinb[l * HD + cl];
                const float c1 = cosb[l * HD + 16 + cl], s1 = sinb[l * HD + 16 + cl];
                const float v0 = acc[rt][0][r] * c0 - acc[rt][2][r] * s0;
                const float v1 = acc[rt][1][r] * c1 - acc[rt][3][r] * s1;
                const float v2 = acc[rt][2][r] * c0 + acc[rt][0][r] * s0;
                const float v3 = acc[rt][3][r] * c1 + acc[rt][1][r] * s1;
                short4v o4;
                o4[0] = (short)f2b(v0 * sc);
                o4[1] = (short)f2b(v1 * sc);
                o4[2] = (short)f2b(v2 * sc);
                o4[3] = (short)f2b(v3 * sc);
                *(short4v*)(dst + (((size_t)b * NH + h) * SEQ + l) * HD + cl * 4) = o4;
            }
        }
    } else {
        #pragma unroll
        for (int rt = 0; rt < 4; ++rt)
            #pragma unroll
            for (int ct = 0; ct < 4; ++ct) {
                const int d = ct * 16 + cl;
                const int l = lbase + rt * 16 + qd * 4;
                short4v o4;
                #pragma unroll
                for (int r = 0; r < 4; ++r) o4[r] = (short)f2b(acc[rt][ct][r]);
                *(short4v*)(vt + (((size_t)b * NH + h) * HD + d) * SEQ + l) = o4;
            }
    }
}

// ---------------------------------------------------------------------------
// GEMM2: out = ob @ wob^T, 128x64 tiles (512 blocks -> 2 blocks/CU), fp32
// store. 4-buffer PAIR staging (R10-verified). XCD-aware swizzle (R11).
// ---------------------------------------------------------------------------
__device__ __forceinline__ void go_stage(const ushort_t* __restrict__ Ag,
                                         const ushort_t* __restrict__ Bg,
                                         ushort_t* As, ushort_t* Bs,
                                         int k0, int w, int lane)
{
    #pragma unroll
    for (int j = 0; j < 2; ++j) {
        const int r = w * 32 + j * 16 + (lane >> 2);
        const int c = (lane & 3) ^ (r & 3);
        ASYNC_COPY16(Ag + (size_t)r * K_DIM + k0 + c * 8, As + (w * 128 + j * 64) * 8);
    }
    const int rb = w * 16 + (lane >> 2);
    const int cb = (lane & 3) ^ (rb & 3);
    ASYNC_COPY16(Bg + (size_t)rb * K_DIM + k0 + cb * 8, Bs + (w * 64) * 8);
}

__global__ __launch_bounds__(256, 3)
void gemm_out_mfma(const ushort_t* __restrict__ ob, const ushort_t* __restrict__ wob,
                   float* __restrict__ out)
{
    __shared__ __align__(16) ushort_t As[4][128 * 32];   // 32KB
    __shared__ __align__(16) ushort_t Bs[4][64 * 32];    // 16KB
    const int id  = blockIdx.y * 16 + blockIdx.x;        // 0..511
    const int id2 = (id & 7) * 64 + (id >> 3);           // XCD-contiguous
    const int bx  = id2 & 15, by = id2 >> 4;
    const int m0 = by * 128, n0 = bx * 64;
    const int t = threadIdx.x;
    const int w = t >> 6, lane = t & 63;
    const int qd = lane >> 4, cl = lane & 15;
    const int wr = w >> 1, wc = w & 1;

    f32x4 acc[4][2];
    #pragma unroll
    for (int i = 0; i < 4; ++i)
        #pragma unroll
        for (int j = 0; j < 2; ++j)
            #pragma unroll
            for (int r = 0; r < 4; ++r) acc[i][j][r] = 0.f;

    const ushort_t* Ag = ob  + (size_t)m0 * K_DIM;
    const ushort_t* Bg = wob + (size_t)n0 * K_DIM;

    const ushort_t* aB[4];
    const ushort_t* bB[2];
    #pragma unroll
    for (int rt = 0; rt < 4; ++rt) {
        const int row = wr * 64 + rt * 16 + cl;
        aB[rt] = As[0] + row * 32 + ((qd ^ (row & 3)) * 8);
    }
    #pragma unroll
    for (int ct = 0; ct < 2; ++ct) {
        const int col = wc * 32 + ct * 16 + cl;
        bB[ct] = Bs[0] + col * 32 + ((qd ^ (col & 3)) * 8);
    }

    // prologue: stage steps 0,1 into buffers 0,1
    go_stage(Ag, Bg, As[0], Bs[0], 0,  w, lane);
    go_stage(Ag, Bg, As[1], Bs[1], 32, w, lane);

    #define GO_STEP(BUF)                                                        \
        {                                                                       \
            short8 af[4], bfr[2];                                               \
            _Pragma("unroll")                                                   \
            for (int rt = 0; rt < 4; ++rt)                                      \
                af[rt] = *(const short8*)(aB[rt] + (BUF) * 4096);               \
            _Pragma("unroll")                                                   \
            for (int ct = 0; ct < 2; ++ct)                                      \
                bfr[ct] = *(const short8*)(bB[ct] + (BUF) * 2048);              \
            _Pragma("unroll")                                                   \
            for (int rt = 0; rt < 4; ++rt)                                      \
                _Pragma("unroll")                                               \
                for (int ct = 0; ct < 2; ++ct)                                  \
                    acc[rt][ct] = __builtin_amdgcn_mfma_f32_16x16x32_bf16(      \
                        af[rt], bfr[ct], acc[rt][ct], 0, 0, 0);                 \
        }

    for (int r = 0; r < K_DIM / 128; ++r) {          // 8 rounds x 4 steps
        __syncthreads();
        go_stage(Ag, Bg, As[2], Bs[2], (4 * r + 2) * 32, w, lane);
        go_stage(Ag, Bg, As[3], Bs[3], (4 * r + 3) * 32, w, lane);
        GO_STEP(0)
        GO_STEP(1)
        __syncthreads();
        if (r + 1 < K_DIM / 128) {
            go_stage(Ag, Bg, As[0], Bs[0], (4 * r + 4) * 32, w, lane);
            go_stage(Ag, Bg, As[1], Bs[1], (4 * r + 5) * 32, w, lane);
        }
        GO_STEP(2)
        GO_STEP(3)
    }
    #undef GO_STEP

    const int mbase = m0 + wr * 64, nbase = n0 + wc * 32;
    #pragma unroll
    for (int rt = 0; rt < 4; ++rt)
        #pragma unroll
        for (int ct = 0; ct < 2; ++ct)
            #pragma unroll
            for (int r = 0; r < 4; ++r)
                out[(size_t)(mbase + rt * 16 + qd * 4 + r) * DIM + nbase + ct * 16 + cl] =
                    acc[rt][ct][r];
}

// ---------------------------------------------------------------------------
// Flash attention v11 (R6/R10/R12-verified, ~55us): pair processing -- one
// __syncthreads + one vmcnt-drain per 128 k-positions. 4 K-buffers + 4
// V-buffers (64KB LDS, 2 blocks/CU). PV-deferral across tiles/barriers via
// alternating register sets.
// Ledger: no VGPR cap <128 (R7 spill); no <2 waves/SIMD (R9); nt>2, split-K
// null (R8/R9); V stays LDS-staged (R5 fail). Grid h-fastest = XCD-local K/V.
// ---------------------------------------------------------------------------
#define QK_MFMA(kfv, sdst)                                                      \
    _Pragma("unroll")                                                           \
    for (int mt = 0; mt < 4; ++mt)                                              \
        _Pragma("unroll")                                                       \
        for (int nt = 0; nt < 2; ++nt)                                          \
            sdst[mt][nt] = __builtin_amdgcn_mfma_f32_16x16x32_bf16(             \
                kfv[mt][0], qf[nt][0], fz, 0, 0, 0);                            \
    _Pragma("unroll")                                                           \
    for (int mt = 0; mt < 4; ++mt)                                              \
        _Pragma("unroll")                                                       \
        for (int nt = 0; nt < 2; ++nt)                                          \
            sdst[mt][nt] = __builtin_amdgcn_mfma_f32_16x16x32_bf16(             \
                kfv[mt][1], qf[nt][1], sdst[mt][nt], 0, 0, 0);

#define PV_MFMA(vfv, pfv)                                                       \
    _Pragma("unroll")                                                           \
    for (int kh = 0; kh < 2; ++kh)                                              \
        _Pragma("unroll")                                                       \
        for (int dt = 0; dt < 4; ++dt)                                          \
            _Pragma("unroll")                                                   \
            for (int nt = 0; nt < 2; ++nt)                                      \
                oaccT[dt][nt] = __builtin_amdgcn_mfma_f32_16x16x32_bf16(        \
                    vfv[dt][kh], pfv[nt][kh], oaccT[dt][nt], 0, 0, 0);

#define L_MFMA(pfv)                                                             \
    _Pragma("unroll")                                                           \
    for (int kh = 0; kh < 2; ++kh)                                              \
        _Pragma("unroll")                                                       \
        for (int nt = 0; nt < 2; ++nt)                                          \
            lacc[nt] = __builtin_amdgcn_mfma_f32_16x16x32_bf16(                 \
                onesA, pfv[nt][kh], lacc[nt], 0, 0, 0);

#define EXPPACK(sv, pfD)                                                        \
    _Pragma("unroll")                                                           \
    for (int nt = 0; nt < 2; ++nt) {                                            \
        unsigned int wr2[4][2];                                                 \
        _Pragma("unroll")                                                       \
        for (int mt = 0; mt < 4; ++mt) {                                        \
            const float e0 = __builtin_amdgcn_exp2f(sv[mt][nt][0]);             \
            const float e1 = __builtin_amdgcn_exp2f(sv[mt][nt][1]);             \
            const float e2 = __builtin_amdgcn_exp2f(sv[mt][nt][2]);             \
            const float e3 = __builtin_amdgcn_exp2f(sv[mt][nt][3]);             \
            union { __hip_bfloat162 h2; unsigned int u; } pk0, pk1;             \
            pk0.h2 = __float22bfloat162_rn(make_float2(e0, e1));                \
            pk1.h2 = __float22bfloat162_rn(make_float2(e2, e3));                \
            wr2[mt][0] = pk0.u;                                                 \
            wr2[mt][1] = pk1.u;                                                 \
        }                                                                       \
        _Pragma("unroll")                                                       \
        for (int kh = 0; kh < 2; ++kh) {                                        \
            union { unsigned int u[4]; short8 s8; } pu;                         \
            _Pragma("unroll")                                                   \
            for (int i = 0; i < 2; ++i) {                                       \
                unsigned int a  = wr2[2 * kh][i];                               \
                unsigned int bb = wr2[2 * kh + 1][i];                           \
                asm("v_permlane32_swap_b32 %0, %1" : "+v"(a), "+v"(bb));        \
                asm("v_permlane16_swap_b32 %0, %1" : "+v"(a), "+v"(bb));        \
                pu.u[i]     = a;                                                \
                pu.u[2 + i] = bb;                                               \
            }                                                                   \
            pfD[nt][kh] = pu.s8;                                                \
        }                                                                       \
    }

// One pair: tile A in buffer at BOFF, tile B at BOFF+4096 (ushort units).
// Consumes persistent set (pfC,vfC); produces (pfP,vfP).
#define PAIR_BODY(BOFF, pfC, vfC, pfP, vfP)                                     \
    {                                                                           \
        short8 kf[4][2], vfT[4][2], pfT[2][2];                                  \
        f32x4 s[4][2];                                                          \
        /* ---- tile A ---- */                                                  \
        _Pragma("unroll")                                                       \
        for (int mt = 0; mt < 4; ++mt) {                                        \
            kf[mt][0] = *(const short8*)(kb0 + (BOFF) + mt * 1024);             \
            kf[mt][1] = *(const short8*)(kb1 + (BOFF) + mt * 1024);             \
        }                                                                       \
        _Pragma("unroll")                                                       \
        for (int dt = 0; dt < 4; ++dt) {                                        \
            vfT[dt][0] = *(const short8*)(vb0 + (BOFF) + dt * 1024);            \
            vfT[dt][1] = *(const short8*)(vb1 + (BOFF) + dt * 1024);            \
        }                                                                       \
        __builtin_amdgcn_s_setprio(1);                                          \
        QK_MFMA(kf, s)                                                          \
        PV_MFMA(vfC, pfC)                                                       \
        __builtin_amdgcn_s_setprio(0);                                          \
        EXPPACK(s, pfT)                                                         \
        L_MFMA(pfT)                                                             \
        /* ---- tile B ---- */                                                  \
        _Pragma("unroll")                                                       \
        for (int mt = 0; mt < 4; ++mt) {                                        \
            kf[mt][0] = *(const short8*)(kb0 + (BOFF) + 4096 + mt * 1024);      \
            kf[mt][1] = *(const short8*)(kb1 + (BOFF) + 4096 + mt * 1024);      \
        }                                                                       \
        _Pragma("unroll")                                                       \
        for (int dt = 0; dt < 4; ++dt) {                                        \
            vfP[dt][0] = *(const short8*)(vb0 + (BOFF) + 4096 + dt * 1024);     \
            vfP[dt][1] = *(const short8*)(vb1 + (BOFF) + 4096 + dt * 1024);     \
        }                                                                       \
        __builtin_amdgcn_s_setprio(1);                                          \
        QK_MFMA(kf, s)                                                          \
        PV_MFMA(vfT, pfT)                                                       \
        __builtin_amdgcn_s_setprio(0);                                          \
        EXPPACK(s, pfP)                                                         \
        L_MFMA(pfP)                                                             \
    }

__global__ __launch_bounds__(256, 2)
void attn_mfma(const ushort_t* __restrict__ qb, const ushort_t* __restrict__ kb,
               const ushort_t* __restrict__ vt, ushort_t* __restrict__ ob)
{
    const int h = blockIdx.x;                 // fastest -> K/V sharers on one XCD
    const int b = blockIdx.y;
    const int qt = blockIdx.z;                // 0..15, 128 queries per block
    const int t = threadIdx.x;
    const int w = t >> 6, lane = t & 63;
    const int qd = lane >> 4, cl = lane & 15;

    __shared__ __align__(16) ushort_t Ks[4][64 * 64];   // 32KB
    __shared__ __align__(16) ushort_t Vs[4][64 * 64];   // 32KB

    const size_t bh = (size_t)b * NH + h;
    const ushort_t* qbase = qb + (bh * SEQ + qt * 128 + w * 32) * HD;
    const ushort_t* kbase = kb + bh * SEQ * HD;
    const ushort_t* vbase = vt + bh * (size_t)HD * SEQ;

    const int p0 = w * 128 + lane;
    const int r0a = p0 >> 3,  c0a = (p0 & 7) ^ (r0a & 7);
    const int p1 = p0 + 64;
    const int r1a = p1 >> 3,  c1a = (p1 & 7) ^ (r1a & 7);
    const int ldsoff0 = (w * 128) * 8;
    const int ldsoff1 = (w * 128 + 64) * 8;

    // staging pointers, advanced two 64-tiles per stage
    const ushort_t* kg0 = kbase + (size_t)r0a * HD + c0a * 8;
    const ushort_t* kg1 = kbase + (size_t)r1a * HD + c1a * 8;
    const ushort_t* vg0 = vbase + (size_t)r0a * SEQ + c0a * 8;
    const ushort_t* vg1 = vbase + (size_t)r1a * SEQ + c1a * 8;

    // hoisted LDS read bases (buffer 0); buffers 1..3 via +4096k immediates
    const int lo0 = (cl * 8 + (qd ^ (cl & 7))) * 8;
    const int lo1 = (cl * 8 + ((4 + qd) ^ (cl & 7))) * 8;
    const ushort_t* kb0 = Ks[0] + lo0; const ushort_t* kb1 = Ks[0] + lo1;
    const ushort_t* vb0 = Vs[0] + lo0; const ushort_t* vb1 = Vs[0] + lo1;

    short8 qf[2][2];
    #pragma unroll
    for (int nt = 0; nt < 2; ++nt)
        #pragma unroll
        for (int kh = 0; kh < 2; ++kh)
            qf[nt][kh] = *(const short8*)(qbase + (nt * 16 + cl) * HD + kh * 32 + qd * 8);

    const f32x4 fz = {0.f, 0.f, 0.f, 0.f};
    short8 onesA;
    #pragma unroll
    for (int e = 0; e < 8; ++e) onesA[e] = (short)0x3F80;   // bf16 1.0

    f32x4 oaccT[4][2];
    f32x4 lacc[2];
    #pragma unroll
    for (int dt = 0; dt < 4; ++dt)
        #pragma unroll
        for (int nt = 0; nt < 2; ++nt)
            #pragma unroll
            for (int r = 0; r < 4; ++r) oaccT[dt][nt][r] = 0.f;
    #pragma unroll
    for (int nt = 0; nt < 2; ++nt)
        #pragma unroll
        for (int r = 0; r < 4; ++r) lacc[nt][r] = 0.f;

    // persistent deferred-PV sets; set-23 zeroed (first pair consumes it)
    short8 pf01[2][2], vf01[4][2], pf23[2][2], vf23[4][2];
    #pragma unroll
    for (int nt = 0; nt < 2; ++nt)
        #pragma unroll
        for (int kh = 0; kh < 2; ++kh)
            #pragma unroll
            for (int e = 0; e < 8; ++e) pf23[nt][kh][e] = 0;
    #pragma unroll
    for (int dt = 0; dt < 4; ++dt)
        #pragma unroll
        for (int kh = 0; kh < 2; ++kh)
            #pragma unroll
            for (int e = 0; e < 8; ++e) vf23[dt][kh][e] = 0;

    {   // stage tiles 0,1 into buffers 0,1
        ASYNC_COPY16(kg0,            (ushort_t*)Ks[0] + ldsoff0);
        ASYNC_COPY16(kg1,            (ushort_t*)Ks[0] + ldsoff1);
        ASYNC_COPY16(vg0,            (ushort_t*)Vs[0] + ldsoff0);
        ASYNC_COPY16(vg1,            (ushort_t*)Vs[0] + ldsoff1);
        ASYNC_COPY16(kg0 + 64 * HD,  (ushort_t*)Ks[1] + ldsoff0);
        ASYNC_COPY16(kg1 + 64 * HD,  (ushort_t*)Ks[1] + ldsoff1);
        ASYNC_COPY16(vg0 + 64,       (ushort_t*)Vs[1] + ldsoff0);
        ASYNC_COPY16(vg1 + 64,       (ushort_t*)Vs[1] + ldsoff1);
        kg0 += 128 * HD; kg1 += 128 * HD; vg0 += 128; vg1 += 128;
    }

    for (int q8 = 0; q8 < 8; ++q8) {
        // ======== pair A: tiles 4q8,4q8+1 in buffers {0,1} ========
        __syncthreads();
        {   // stage tiles 4q8+2,4q8+3 -> buffers {2,3} (always valid)
            ASYNC_COPY16(kg0,            (ushort_t*)Ks[2] + ldsoff0);
            ASYNC_COPY16(kg1,            (ushort_t*)Ks[2] + ldsoff1);
            ASYNC_COPY16(vg0,            (ushort_t*)Vs[2] + ldsoff0);
            ASYNC_COPY16(vg1,            (ushort_t*)Vs[2] + ldsoff1);
            ASYNC_COPY16(kg0 + 64 * HD,  (ushort_t*)Ks[3] + ldsoff0);
            ASYNC_COPY16(kg1 + 64 * HD,  (ushort_t*)Ks[3] + ldsoff1);
            ASYNC_COPY16(vg0 + 64,       (ushort_t*)Vs[3] + ldsoff0);
            ASYNC_COPY16(vg1 + 64,       (ushort_t*)Vs[3] + ldsoff1);
            kg0 += 128 * HD; kg1 += 128 * HD; vg0 += 128; vg1 += 128;
        }
        PAIR_BODY(0, pf23, vf23, pf01, vf01)

        // ======== pair B: tiles 4q8+2,4q8+3 in buffers {2,3} ========
        __syncthreads();
        if (q8 + 1 < 8) {   // stage tiles 4q8+4,4q8+5 -> buffers {0,1}
            ASYNC_COPY16(kg0,            (ushort_t*)Ks[0] + ldsoff0);
            ASYNC_COPY16(kg1,            (ushort_t*)Ks[0] + ldsoff1);
            ASYNC_COPY16(vg0,            (ushort_t*)Vs[0] + ldsoff0);
            ASYNC_COPY16(vg1,            (ushort_t*)Vs[0] + ldsoff1);
            ASYNC_COPY16(kg0 + 64 * HD,  (ushort_t*)Ks[1] + ldsoff0);
            ASYNC_COPY16(kg1 + 64 * HD,  (ushort_t*)Ks[1] + ldsoff1);
            ASYNC_COPY16(vg0 + 64,       (ushort_t*)Vs[1] + ldsoff0);
            ASYNC_COPY16(vg1 + 64,       (ushort_t*)Vs[1] + ldsoff1);
            kg0 += 128 * HD; kg1 += 128 * HD; vg0 += 128; vg1 += 128;
        }
        PAIR_BODY(8192, pf01, vf01, pf23, vf23)
    }

    // tail PV for the last tile (pair B of q8=7 produced pf23/vf23)
    PV_MFMA(vf23, pf23)

    // ---- epilogue: l comes straight from lacc (all rows equal) ----
    #pragma unroll
    for (int nt = 0; nt < 2; ++nt) {
        const float inv = 1.0f / lacc[nt][0];
        const int query = qt * 128 + w * 32 + nt * 16 + cl;
        ushort_t* op = ob + ((size_t)b * SEQ + query) * DIM + h * HD;
        #pragma unroll
        for (int dt = 0; dt < 4; ++dt) {
            short4v o4;
            #pragma unroll
            for (int r = 0; r < 4; ++r) o4[r] = (short)f2b(oaccT[dt][nt][r] * inv);
            *(short4v*)(op + dt * 16 + qd * 4) = o4;
        }
    }
}

// ---------------------------------------------------------------------------
extern "C" void kernel_launch(void* const* d_in, const int* in_sizes, int n_in,
                              void* d_out, int out_size, void* d_ws, size_t ws_size,
                              hipStream_t stream)
{
    const float* x     = (const float*)d_in[0];
    const float* cosb  = (const float*)d_in[1];
    const float* sinb  = (const float*)d_in[2];
    const float* w_qkv = (const float*)d_in[3];
    const float* w_out = (const float*)d_in[4];
    float* out = (float*)d_out;

    // workspace layout (peak 48MB, no aliasing hazards):
    //  [0,8)   qb   [8,16) kb   [16,24) vt   [24,26) wob
    //  [26,34) ob   [34,42) xb  [42,48) wqb
    constexpr size_t MB = 1u << 20;
    char* ws = (char*)d_ws;
    ushort_t* qb  = (ushort_t*)(ws);
    ushort_t* kb  = (ushort_t*)(ws + 8 * MB);
    ushort_t* vt  = (ushort_t*)(ws + 16 * MB);
    ushort_t* wob = (ushort_t*)(ws + 24 * MB);
    ushort_t* ob  = (ushort_t*)(ws + 26 * MB);
    ushort_t* xb  = (ushort_t*)(ws + 34 * MB);
    ushort_t* wqb = (ushort_t*)(ws + 42 * MB);

    prep<<<3072, 256, 0, stream>>>(x, w_qkv, w_out, xb, wqb, wob);
    gemm_qkv_mfma<<<dim3(24, 32), 256, 0, stream>>>(xb, wqb, qb, kb, vt, cosb, sinb);
    attn_mfma<<<dim3(16, 2, 16), 256, 0, stream>>>(qb, kb, vt, ob);
    gemm_out_mfma<<<dim3(16, 32), 256, 0, stream>>>(ob, wob, out);
}